// Round 8
// baseline (7058.000 us; speedup 1.0000x reference)
//
#include <hip/hip_runtime.h>

// ---------------------------------------------------------------------------
// ComNet: R=16 runs x T=512 steps x 32 agents, sequential agent scan.
//   k0: transpose W1[:, :93] -> w1T
//   k1: pre1[rti][h] = b1[h] + xs(93) . W1xs  (parallel, bulk of FLOPs)
//   k2: wave-synchronous sequential kernel, 8 blocks x 1 wave, TWO independent
//       runs interleaved per wave (fills chain-stall cycles with real work).
//       h2 stored fp16 to LDS ring, flushed per-t into the DEAD pre1 row t.
//   k3: ctrl2 epilogue computes o0/o1 from stored h2 (parallel).
// R1: __syncthreads vmcnt(0) drains -> removed. R2: LDS out ring + snapshot.
// R4: clock hypothesis dead. R5: W2 rows into named regs (scratch reloads
// were the stall). R6: fp16 h1 + v_dot2 + clampless tanh. R7: LDS-staged pre1
// (on-chain vmcnt gone); 742 cyc/step = chain + single-wave issue.
// R8: 2-run interleave + o0/o1 deferred to epilogue.
// ---------------------------------------------------------------------------

#define R_RUNS 16
#define T_STEPS 512
#define NA 32
#define HID 64
#define XS 93                       // (NA-1)*3
#define DIN 124
#define STEPS_PER_RUN (T_STEPS * NA)        // 16384
#define RTI_TOT (R_RUNS * STEPS_PER_RUN)    // 262144

#define PRE1_OFF 65536
#define WS_NEEDED ((size_t)PRE1_OFF + (size_t)RTI_TOT * HID * 4 + 4096)

typedef _Float16 half2_t __attribute__((ext_vector_type(2)));

__device__ __forceinline__ float fast_tanh(float x) {
  // tanh(x) = 1 - 2/(e^{2x}+1); exp(+inf)->rcp=0 -> 1; exp(-inf)=0 -> -1.
  float e = __expf(2.f * x);
  return fmaf(-2.f, __builtin_amdgcn_rcpf(e + 1.f), 1.f);
}

__device__ __forceinline__ float dot2h(half2_t a, half2_t b, float c) {
#if __has_builtin(__builtin_amdgcn_fdot2)
  return __builtin_amdgcn_fdot2(a, b, c, false);
#else
  return fmaf((float)a.x, (float)b.x, fmaf((float)a.y, (float)b.y, c));
#endif
}

#define DPP_ADD(x, ctrl, rmask) \
  (x) += __int_as_float(__builtin_amdgcn_update_dpp(0, __float_as_int(x), (ctrl), (rmask), 0xf, true))

__device__ __forceinline__ float wave64_sum_bcast(float x) {
  DPP_ADD(x, 0x111, 0xf);
  DPP_ADD(x, 0x112, 0xf);
  DPP_ADD(x, 0x114, 0xf);
  DPP_ADD(x, 0x118, 0xf);
  DPP_ADD(x, 0x142, 0xa);
  DPP_ADD(x, 0x143, 0xc);
  return __int_as_float(__builtin_amdgcn_readlane(__float_as_int(x), 63));
}

// two interleaved sums, both broadcast (readlane 63)
__device__ __forceinline__ void wave64_sum2_bcast(float& x0, float& x1) {
#define ST2(ctrl, rmask) DPP_ADD(x0, ctrl, rmask); DPP_ADD(x1, ctrl, rmask)
  ST2(0x111, 0xf);
  ST2(0x112, 0xf);
  ST2(0x114, 0xf);
  ST2(0x118, 0xf);
  ST2(0x142, 0xa);
  ST2(0x143, 0xc);
#undef ST2
  x0 = __int_as_float(__builtin_amdgcn_readlane(__float_as_int(x0), 63));
  x1 = __int_as_float(__builtin_amdgcn_readlane(__float_as_int(x1), 63));
}

// two interleaved sums, totals left in lane 63
__device__ __forceinline__ void wave64_sum2_l63(float& x0, float& x1) {
#define ST2(ctrl, rmask) DPP_ADD(x0, ctrl, rmask); DPP_ADD(x1, ctrl, rmask)
  ST2(0x111, 0xf);
  ST2(0x112, 0xf);
  ST2(0x114, 0xf);
  ST2(0x118, 0xf);
  ST2(0x142, 0xa);
  ST2(0x143, 0xc);
#undef ST2
}

// ---------------- k0: transpose W1 xs-part ----------------
__global__ void transpose_w1(const float* __restrict__ w1, float* __restrict__ w1T) {
  int idx = blockIdx.x * blockDim.x + threadIdx.x;  // idx = k*64 + h
  if (idx < XS * HID) {
    int k = idx / HID, h = idx % HID;
    w1T[idx] = w1[h * DIN + k];
  }
}

// ---------------- k1: pre1 = b1 + xs @ W1xs^T ----------------
__global__ __launch_bounds__(256) void pre1_kernel(
    const float* __restrict__ runs, const float* __restrict__ w1T,
    const float* __restrict__ b1, float* __restrict__ pre1) {
  const int wid = (blockIdx.x * 256 + threadIdx.x) >> 6;  // rti, one wave each
  const int lane = threadIdx.x & 63;
  const float* xs = runs + (size_t)wid * XS;   // wave-uniform: broadcast loads
  float a0 = b1[lane], a1 = 0.f, a2 = 0.f;
#pragma unroll 4
  for (int k = 0; k < 31; ++k) {
    a0 = fmaf(xs[3 * k],     w1T[(3 * k) * HID + lane],     a0);
    a1 = fmaf(xs[3 * k + 1], w1T[(3 * k + 1) * HID + lane], a1);
    a2 = fmaf(xs[3 * k + 2], w1T[(3 * k + 2) * HID + lane], a2);
  }
  pre1[(size_t)wid * HID + lane] = (a0 + a1) + a2;
}

// ---------------- k2: sequential core, 2 runs per wave ----------------
// A[h][j] = w1[h][93+j] (j<=30, pad 0) : weight of comm[j] when j<i
// B[h][j] = w1[h][92+j] (j>=1,  pad 0) : weight of comm[j] when j>i
// h1pre = pre1 + FB + Q - S per run. h2 (fp16) -> LDS ring -> dead pre1 row t.
__global__ __launch_bounds__(64, 1) void seq_kernel(
    const float* __restrict__ w1, const float* __restrict__ w2,
    const float* __restrict__ b2, const float* __restrict__ w3,
    const float* __restrict__ b3, const float* __restrict__ comm_init,
    float* __restrict__ pre1) {
  const int h = threadIdx.x;
  const int ra = blockIdx.x * 2, rb = ra + 1;
  const int hb = h * 33;              // stride 33: conflict-free, pad entry 32

  __shared__ float Asl[HID * 33];
  __shared__ float Bsl[HID * 33];
  __shared__ __align__(16) float commLa[NA], commLb[NA];
  __shared__ __align__(16) _Float16 h1sa[HID], h1sb[HID];
  __shared__ __align__(16) _Float16 h2ra[NA * HID], h2rb[NA * HID];  // 4KB each
  __shared__ __align__(16) float pbufa[2][2048 + 64], pbufb[2][2048 + 64];

  for (int j = 0; j < 31; ++j) Asl[hb + j] = w1[h * DIN + 93 + j];
  Asl[hb + 31] = 0.f;
  Asl[hb + 32] = 0.f;                 // pad: A_next read at i=31
  Bsl[hb] = 0.f;
  for (int j = 1; j < 32; ++j) Bsl[hb + j] = w1[h * DIN + 92 + j];
  Bsl[hb + 32] = 0.f;                 // pad: B_next read at i=31

  // W2 row h -> 32 NAMED half2 (no array -> no SROA demotion).
  const float4* w2v = (const float4*)(w2 + h * HID);
  const float4 r0 = w2v[0],  r1 = w2v[1],  r2 = w2v[2],  r3 = w2v[3];
  const float4 r4 = w2v[4],  r5 = w2v[5],  r6 = w2v[6],  r7 = w2v[7];
  const float4 r8 = w2v[8],  r9 = w2v[9],  r10 = w2v[10], r11 = w2v[11];
  const float4 r12 = w2v[12], r13 = w2v[13], r14 = w2v[14], r15 = w2v[15];
#define PK2(n, f4) \
  const half2_t n##a = {(_Float16)(f4).x, (_Float16)(f4).y}; \
  const half2_t n##b = {(_Float16)(f4).z, (_Float16)(f4).w}
  PK2(q0, r0);  PK2(q1, r1);  PK2(q2, r2);  PK2(q3, r3);
  PK2(q4, r4);  PK2(q5, r5);  PK2(q6, r6);  PK2(q7, r7);
  PK2(q8, r8);  PK2(q9, r9);  PK2(q10, r10); PK2(q11, r11);
  PK2(q12, r12); PK2(q13, r13); PK2(q14, r14); PK2(q15, r15);
#undef PK2

  const float b2h = b2[h];
  const float w32h = w3[2 * HID + h];
  const float b32 = b3[2];

  float commRa = (h < NA) ? comm_init[ra * NA + h] : 0.f;
  float commRb = (h < NA) ? comm_init[rb * NA + h] : 0.f;
  if (h < NA) { commLa[h] = commRa; commLb[h] = commRb; }

  float* prow_a = pre1 + (size_t)ra * STEPS_PER_RUN * HID;  // + t*2048 floats
  float* prow_b = pre1 + (size_t)rb * STEPS_PER_RUN * HID;

  // prime rows 0,1 of both runs into the LDS rings
  {
#pragma unroll
    for (int bsel = 0; bsel < 2; ++bsel) {
      const float4* sa = (const float4*)(prow_a + bsel * 2048);
      const float4* sb = (const float4*)(prow_b + bsel * 2048);
      float4* da = (float4*)&pbufa[bsel][0];
      float4* db = (float4*)&pbufb[bsel][0];
#pragma unroll
      for (int j = 0; j < 8; ++j) da[j * 64 + h] = sa[j * 64 + h];
#pragma unroll
      for (int j = 0; j < 8; ++j) db[j * 64 + h] = sb[j * 64 + h];
    }
  }

  for (int t = 0; t < T_STEPS; ++t) {
    float* pba = pbufa[t & 1];
    float* pbb = pbufb[t & 1];
    // prefetch row t+2 (both runs) into named regs; consumed by the
    // end-of-t ds_writes — a full ~15k-cyc body away, fully off-chain.
    int tk = (t + 2 <= T_STEPS - 1) ? t + 2 : T_STEPS - 1;
    const float4* gsa = (const float4*)(prow_a + (size_t)tk * 2048);
    const float4* gsb = (const float4*)(prow_b + (size_t)tk * 2048);
    float4 ga0 = gsa[0 * 64 + h], ga1 = gsa[1 * 64 + h];
    float4 ga2 = gsa[2 * 64 + h], ga3 = gsa[3 * 64 + h];
    float4 ga4 = gsa[4 * 64 + h], ga5 = gsa[5 * 64 + h];
    float4 ga6 = gsa[6 * 64 + h], ga7 = gsa[7 * 64 + h];
    float4 gb0 = gsb[0 * 64 + h], gb1 = gsb[1 * 64 + h];
    float4 gb2 = gsb[2 * 64 + h], gb3 = gsb[3 * 64 + h];
    float4 gb4 = gsb[4 * 64 + h], gb5 = gsb[5 * 64 + h];
    float4 gb6 = gsb[6 * 64 + h], gb7 = gsb[7 * 64 + h];

    // FB refresh for both runs (amortized over 32 steps)
    const float4* ca4 = (const float4*)commLa;
    const float4* cb4 = (const float4*)commLb;
    float fa0 = 0.f, fa1 = 0.f, fb0 = 0.f, fb1 = 0.f;
#pragma unroll
    for (int q = 0; q < 8; ++q) {
      float4 ca = ca4[q];
      float4 cb = cb4[q];
      float w0 = Bsl[hb + 4 * q + 0], w1_ = Bsl[hb + 4 * q + 1];
      float w2_ = Bsl[hb + 4 * q + 2], w3_ = Bsl[hb + 4 * q + 3];
      fa0 = fmaf(w0, ca.x, fa0); fa1 = fmaf(w1_, ca.y, fa1);
      fa0 = fmaf(w2_, ca.z, fa0); fa1 = fmaf(w3_, ca.w, fa1);
      fb0 = fmaf(w0, cb.x, fb0); fb1 = fmaf(w1_, cb.y, fb1);
      fb0 = fmaf(w2_, cb.z, fb0); fb1 = fmaf(w3_, cb.w, fb1);
    }
    const float FBa = fa0 + fa1;
    const float FBb = fb0 + fb1;
    const float c0sa = commRa, c0sb = commRb;   // t-start snapshots
    float Qa = 0.f, Sa = 0.f, Qb = 0.f, Sb = 0.f;
    float pfa = pba[h], pfb = pbb[h];
    float A_cur = Asl[hb], B_cur = Bsl[hb];

#pragma unroll 4
    for (int i = 0; i < NA; ++i) {
      float pfa_n = pba[(i + 1) * 64 + h];   // i=31 -> pad slot, unused
      float pfb_n = pbb[(i + 1) * 64 + h];
      float A_n = Asl[hb + i + 1];
      float B_n = Bsl[hb + i + 1];
      float olda = __int_as_float(__builtin_amdgcn_readlane(__float_as_int(c0sa), i));
      float oldb = __int_as_float(__builtin_amdgcn_readlane(__float_as_int(c0sb), i));
      Sa = fmaf(B_cur, olda, Sa);
      Sb = fmaf(B_cur, oldb, Sb);
      float h1a = fast_tanh(pfa + (FBa - Sa) + Qa);
      float h1b = fast_tanh(pfb + (FBb - Sb) + Qb);
      h1sa[h] = (_Float16)h1a;
      h1sb[h] = (_Float16)h1b;
      const uint4* hva = (const uint4*)h1sa;   // broadcast reads, 8 b128 each
      const uint4* hvb = (const uint4*)h1sb;
      uint4 XA0 = hva[0], XA1 = hva[1], XA2 = hva[2], XA3 = hva[3];
      uint4 XA4 = hva[4], XA5 = hva[5], XA6 = hva[6], XA7 = hva[7];
      uint4 XB0 = hvb[0], XB1 = hvb[1], XB2 = hvb[2], XB3 = hvb[3];
      uint4 XB4 = hvb[4], XB5 = hvb[5], XB6 = hvb[6], XB7 = hvb[7];
#define BC(u) __builtin_bit_cast(half2_t, (u))
      float aa0 = b2h, aa1 = 0.f, aa2 = 0.f, aa3 = 0.f;
      float ab0 = b2h, ab1 = 0.f, ab2 = 0.f, ab3 = 0.f;
#define DOTB(acc0, acc1, acc2, acc3, Xq, qe, qo) \
      acc0 = dot2h(qe##a, BC(Xq.x), acc0); acc1 = dot2h(qe##b, BC(Xq.y), acc1); \
      acc2 = dot2h(qo##a, BC(Xq.z), acc2); acc3 = dot2h(qo##b, BC(Xq.w), acc3)
      DOTB(aa0, aa1, aa2, aa3, XA0, q0, q1);
      DOTB(ab0, ab1, ab2, ab3, XB0, q0, q1);
      DOTB(aa0, aa1, aa2, aa3, XA1, q2, q3);
      DOTB(ab0, ab1, ab2, ab3, XB1, q2, q3);
      DOTB(aa0, aa1, aa2, aa3, XA2, q4, q5);
      DOTB(ab0, ab1, ab2, ab3, XB2, q4, q5);
      DOTB(aa0, aa1, aa2, aa3, XA3, q6, q7);
      DOTB(ab0, ab1, ab2, ab3, XB3, q6, q7);
      DOTB(aa0, aa1, aa2, aa3, XA4, q8, q9);
      DOTB(ab0, ab1, ab2, ab3, XB4, q8, q9);
      DOTB(aa0, aa1, aa2, aa3, XA5, q10, q11);
      DOTB(ab0, ab1, ab2, ab3, XB5, q10, q11);
      DOTB(aa0, aa1, aa2, aa3, XA6, q12, q13);
      DOTB(ab0, ab1, ab2, ab3, XB6, q12, q13);
      DOTB(aa0, aa1, aa2, aa3, XA7, q14, q15);
      DOTB(ab0, ab1, ab2, ab3, XB7, q14, q15);
#undef DOTB
#undef BC
      float h2a = fast_tanh((aa0 + aa1) + (aa2 + aa3));
      float h2b = fast_tanh((ab0 + ab1) + (ab2 + ab3));
      h2ra[i * 64 + h] = (_Float16)h2a;   // for epilogue; off-chain
      h2rb[i * 64 + h] = (_Float16)h2b;
      float cna = w32h * h2a, cnb = w32h * h2b;
      wave64_sum2_bcast(cna, cnb);        // 2-interleaved DPP chains
      float c_new_a = cna + b32;
      float c_new_b = cnb + b32;
      Qa = fmaf(A_cur, c_new_a, Qa);
      Qb = fmaf(A_cur, c_new_b, Qb);
      commRa = (h == i) ? c_new_a : commRa;
      commRb = (h == i) ? c_new_b : commRb;
      pfa = pfa_n; pfb = pfb_n; A_cur = A_n; B_cur = B_n;
    }
    if (h < NA) { commLa[h] = commRa; commLb[h] = commRb; }
    // flush h2 rings (4KB each) into the DEAD pre1 rows t (same linear order).
    {
      const uint4* qa = (const uint4*)h2ra;
      const uint4* qb = (const uint4*)h2rb;
      uint4* oa = (uint4*)(prow_a + (size_t)t * 2048);
      uint4* ob = (uint4*)(prow_b + (size_t)t * 2048);
#pragma unroll
      for (int j = 0; j < 4; ++j) oa[j * 64 + h] = qa[j * 64 + h];
#pragma unroll
      for (int j = 0; j < 4; ++j) ob[j * 64 + h] = qb[j * 64 + h];
    }
    // stage row t+2 into the buffers just freed (g-regs retired long ago).
    float4* pda = (float4*)pba;
    float4* pdb = (float4*)pbb;
    pda[0 * 64 + h] = ga0; pda[1 * 64 + h] = ga1;
    pda[2 * 64 + h] = ga2; pda[3 * 64 + h] = ga3;
    pda[4 * 64 + h] = ga4; pda[5 * 64 + h] = ga5;
    pda[6 * 64 + h] = ga6; pda[7 * 64 + h] = ga7;
    pdb[0 * 64 + h] = gb0; pdb[1 * 64 + h] = gb1;
    pdb[2 * 64 + h] = gb2; pdb[3 * 64 + h] = gb3;
    pdb[4 * 64 + h] = gb4; pdb[5 * 64 + h] = gb5;
    pdb[6 * 64 + h] = gb6; pdb[7 * 64 + h] = gb7;
  }
}

// ---------------- k3: ctrl epilogue from stored h2 ----------------
__global__ __launch_bounds__(256) void ctrl2_kernel(
    const float* __restrict__ pre1h2, const float* __restrict__ w3,
    const float* __restrict__ b3, float* __restrict__ out) {
  const int wid = (blockIdx.x * 256 + threadIdx.x) >> 6;  // global step id
  const int lane = threadIdx.x & 63;
  const int r = wid >> 14;             // 16384 steps per run
  const int rem = wid & 16383;
  const int t = rem >> 5, i = rem & 31;
  const _Float16* hp =
      (const _Float16*)(pre1h2 + ((size_t)(r * T_STEPS + t)) * 2048);
  float h2v = (float)hp[i * 64 + lane];
  float o0 = w3[lane] * h2v;
  float o1 = w3[HID + lane] * h2v;
  wave64_sum2_l63(o0, o1);
  if (lane == 63)
    ((float2*)out)[wid] = make_float2(o0 + b3[0], o1 + b3[1]);
}

// ---------------- fallback: fully fused, zero workspace (unused when ws ok) --
__global__ __launch_bounds__(64, 1) void seq_fused(
    const float* __restrict__ runs, const float* __restrict__ comm_init,
    const float* __restrict__ w1, const float* __restrict__ b1,
    const float* __restrict__ w2, const float* __restrict__ b2,
    const float* __restrict__ w3, const float* __restrict__ b3,
    float* __restrict__ out) {
  const int r = blockIdx.x;
  const int h = threadIdx.x;
  const int hb = h * 33;

  __shared__ float Asl[HID * 33];
  __shared__ float Bsl[HID * 33];
  __shared__ float commL[NA];
  __shared__ __align__(16) float h1s[HID];
  __shared__ float w1xs[XS * HID];
  __shared__ __align__(16) float xsl[96];

  for (int j = 0; j < 31; ++j) Asl[hb + j] = w1[h * DIN + 93 + j];
  Asl[hb + 31] = 0.f;
  Bsl[hb] = 0.f;
  for (int j = 1; j < 32; ++j) Bsl[hb + j] = w1[h * DIN + 92 + j];
  for (int k = 0; k < XS; ++k) w1xs[k * HID + h] = w1[h * DIN + k];

  float w2r[HID];
#pragma unroll
  for (int k = 0; k < HID; ++k) w2r[k] = w2[h * HID + k];
  const float b1h = b1[h];
  const float b2h = b2[h];
  const float w30h = w3[h], w31h = w3[HID + h], w32h = w3[2 * HID + h];
  const float b30 = b3[0], b31 = b3[1], b32 = b3[2];
  if (h < NA) commL[h] = comm_init[r * NA + h];

  const float* xbase = runs + (size_t)r * STEPS_PER_RUN * XS;
  float xa = xbase[h];
  float xb = (h < XS - 64) ? xbase[64 + h] : 0.f;
  float* outp = out + (size_t)r * STEPS_PER_RUN * 2;
  __syncthreads();

  int s = 0;
  for (int t = 0; t < T_STEPS; ++t) {
    float FB = 0.f;
#pragma unroll
    for (int j = 0; j < NA; ++j) FB = fmaf(Bsl[hb + j], commL[j], FB);
    float Q = 0.f, S = 0.f;
    for (int i = 0; i < NA; ++i, ++s) {
      int sn = s + 1; if (sn > STEPS_PER_RUN - 1) sn = STEPS_PER_RUN - 1;
      const float* xn = xbase + (size_t)sn * XS;
      xsl[h] = xa;
      if (h < XS - 64) xsl[64 + h] = xb;
      __syncthreads();
      float xa_n = xn[h];
      float xb_n = (h < XS - 64) ? xn[64 + h] : 0.f;
      float a0 = b1h, a1 = 0.f, a2 = 0.f;
#pragma unroll 4
      for (int k = 0; k < 31; ++k) {
        a0 = fmaf(xsl[3 * k],     w1xs[(3 * k) * HID + h],     a0);
        a1 = fmaf(xsl[3 * k + 1], w1xs[(3 * k + 1) * HID + h], a1);
        a2 = fmaf(xsl[3 * k + 2], w1xs[(3 * k + 2) * HID + h], a2);
      }
      float old_i = commL[i];
      S = fmaf(Bsl[hb + i], old_i, S);
      float h1 = fast_tanh(((a0 + a1) + a2) + FB + Q - S);
      h1s[h] = h1;
      __syncthreads();
      float c0 = b2h, c1 = 0.f, c2 = 0.f, c3 = 0.f;
      const float4* hv4 = (const float4*)h1s;
#pragma unroll
      for (int k4 = 0; k4 < 16; ++k4) {
        float4 hv = hv4[k4];
        c0 = fmaf(w2r[4 * k4 + 0], hv.x, c0);
        c1 = fmaf(w2r[4 * k4 + 1], hv.y, c1);
        c2 = fmaf(w2r[4 * k4 + 2], hv.z, c2);
        c3 = fmaf(w2r[4 * k4 + 3], hv.w, c3);
      }
      float h2 = fast_tanh((c0 + c1) + (c2 + c3));
      float o0 = wave64_sum_bcast(w30h * h2) + b30;
      float o1 = wave64_sum_bcast(w31h * h2) + b31;
      float c_new = wave64_sum_bcast(w32h * h2) + b32;
      if (h == 0) *(float2*)(outp + (size_t)s * 2) = make_float2(o0, o1);
      Q = fmaf(Asl[hb + i], c_new, Q);
      if (h == i) commL[h] = c_new;
      __syncthreads();
      xa = xa_n; xb = xb_n;
    }
  }
}

extern "C" void kernel_launch(void* const* d_in, const int* in_sizes, int n_in,
                              void* d_out, int out_size, void* d_ws, size_t ws_size,
                              hipStream_t stream) {
  const float* runs = (const float*)d_in[0];
  const float* comm_init = (const float*)d_in[1];
  const float* w1 = (const float*)d_in[2];
  const float* b1 = (const float*)d_in[3];
  const float* w2 = (const float*)d_in[4];
  const float* b2 = (const float*)d_in[5];
  const float* w3 = (const float*)d_in[6];
  const float* b3 = (const float*)d_in[7];
  float* out = (float*)d_out;

  if (ws_size >= WS_NEEDED) {
    float* w1T = (float*)d_ws;
    float* pre1 = (float*)((char*)d_ws + PRE1_OFF);
    hipLaunchKernelGGL(transpose_w1, dim3((XS * HID + 255) / 256), dim3(256), 0, stream,
                       w1, w1T);
    hipLaunchKernelGGL(pre1_kernel, dim3(RTI_TOT / 4), dim3(256), 0, stream,
                       runs, w1T, b1, pre1);
    hipLaunchKernelGGL(seq_kernel, dim3(R_RUNS / 2), dim3(64), 0, stream,
                       w1, w2, b2, w3, b3, comm_init, pre1);
    hipLaunchKernelGGL(ctrl2_kernel, dim3(RTI_TOT / 4), dim3(256), 0, stream,
                       pre1, w3, b3, out);
  } else {
    hipLaunchKernelGGL(seq_fused, dim3(R_RUNS), dim3(64), 0, stream,
                       runs, comm_init, w1, b1, w2, b2, w3, b3, out);
  }
}